// Round 3
// baseline (3739.988 us; speedup 1.0000x reference)
//
#include <hip/hip_runtime.h>
#include <hip/hip_bf16.h>

#define NBLK 64
#define NTHR 256

typedef __attribute__((ext_vector_type(8))) short short8;
typedef __attribute__((ext_vector_type(4))) float f32x4;

constexpr int B = 32, T = 512, D = 1024;
constexpr int JW = D / NBLK;           // 16 h-columns per block
constexpr int KW = D / 4;              // 256 K-elements per wave (K-split)
constexpr int RING = 4;                // s-buffer ring slots
static_assert(JW * NBLK == D, "partition");

__device__ __forceinline__ unsigned short f2bf(float f) {
  unsigned u = __builtin_bit_cast(unsigned, f);
  u += 0x7FFFu + ((u >> 16) & 1u);     // RNE
  return (unsigned short)(u >> 16);
}

__device__ __forceinline__ float sigm(float v) {
  return 1.0f / (1.0f + __expf(-v));
}

__device__ __forceinline__ float tanh_fast(float v) {
  v = fminf(fmaxf(v, -30.0f), 30.0f);
  float e = __expf(2.0f * v);
  return (e - 1.0f) / (e + 1.0f);
}

// agent-scope (LLC-coherent, L2-bypass) relaxed ops — no cache fences anywhere
__device__ __forceinline__ void st_u32_llc(unsigned* p, unsigned v) {
  __hip_atomic_store(p, v, __ATOMIC_RELAXED, __HIP_MEMORY_SCOPE_AGENT);
}
__device__ __forceinline__ unsigned long long ld_u64_llc(const void* p) {
  return __hip_atomic_load((const unsigned long long*)p, __ATOMIC_RELAXED,
                           __HIP_MEMORY_SCOPE_AGENT);
}

struct ull2s { unsigned long long lo, hi; };

__global__ void __launch_bounds__(NTHR, 1) lstm_persistent(
    const float* __restrict__ x,
    const float* __restrict__ W1, const float* __restrict__ b1,
    const float* __restrict__ W2, const float* __restrict__ b2,
    const float* __restrict__ W3, const float* __restrict__ b3,
    const float* __restrict__ W4, const float* __restrict__ b4,
    const float* __restrict__ bias,
    float* __restrict__ out,            // [B,T,D] ++ cT [B,D] ++ hT [B,D]
    unsigned short* __restrict__ sbuf)  // [RING][B][D] bf16 bits, 0xFFFF = not-ready
{
  __shared__ float zx[4][B][66];        // padded gate-exchange

  const int blk  = blockIdx.x;
  const int tid  = threadIdx.x;
  const int wave = tid >> 6;
  const int lane = tid & 63;
  const int j0   = blk * JW;

  const int col   = lane & 15;          // m-row / n-col within 16x16 tile
  const int kg    = (lane >> 4) * 8;    // k sub-offset within a K=32 step
  const int kbase = wave * KW;          // this wave's K slice

  // ---- one-time: weights for ALL 4 gates over this wave's K slice ----
  const float* Wg[4] = {W1, W2, W3, W4};
  short8 bfrag[4][8];
#pragma unroll
  for (int g = 0; g < 4; ++g) {
    const float* wrow = Wg[g] + (size_t)(j0 + col) * D + kbase;
#pragma unroll
    for (int kk = 0; kk < 8; ++kk) {
      float4 fa = *(const float4*)(wrow + kk * 32 + kg);
      float4 fb = *(const float4*)(wrow + kk * 32 + kg + 4);
      short8 v;
      v[0] = (short)f2bf(fa.x); v[1] = (short)f2bf(fa.y);
      v[2] = (short)f2bf(fa.z); v[3] = (short)f2bf(fa.w);
      v[4] = (short)f2bf(fb.x); v[5] = (short)f2bf(fb.y);
      v[6] = (short)f2bf(fb.z); v[7] = (short)f2bf(fb.w);
      bfrag[g][kk] = v;
    }
  }

  // ---- gate-math thread mapping: batch row gb, h-columns (jp, jp+1) ----
  const int gb   = tid >> 3;            // 0..31
  const int jp   = (tid & 7) * 2;       // 0,2,..,14
  const int jcol = j0 + jp;

  const float bsum0 = bias[jcol], bsum1 = bias[jcol + 1];
  const float bf0 = b1[jcol] + bsum0, bf1 = b1[jcol + 1] + bsum1;
  const float bi0 = b2[jcol] + bsum0, bi1 = b2[jcol + 1] + bsum1;
  const float bg0 = b3[jcol] + bsum0, bg1 = b3[jcol + 1] + bsum1;
  const float bo0 = b4[jcol] + bsum0, bo1 = b4[jcol + 1] + bsum1;

  // ---- publish s_0 = x[:,0,:] slice into ring slot 0 (no drain, no flag) ----
  {
    float2 x0 = *(const float2*)(x + (size_t)gb * T * D + jcol);
    st_u32_llc((unsigned*)(sbuf + (size_t)gb * D + jcol),
               (unsigned)f2bf(x0.x) | ((unsigned)f2bf(x0.y) << 16));
  }

  float c0 = 0.0f, c1 = 0.0f;

  for (int t = 0; t < T; ++t) {
    const unsigned short* s = sbuf + (size_t)(t & 3) * B * D;

    // reset own region of slot (t+2)&3 to sentinel (safe: step t-1 poll passed
    // => every block consumed s_{t-2}, the old content of that slot)
    if (t + 2 < T) {
      unsigned short* srst = sbuf + (size_t)((t + 2) & 3) * B * D;
      st_u32_llc((unsigned*)(srst + (size_t)gb * D + jcol), 0xFFFFFFFFu);
    }

    // prefetch x[t+1] slice (normal cached load, overlaps the poll)
    float xa = 0.0f, xb = 0.0f;
    if (t + 1 < T) {
      float2 xn = *(const float2*)(x + (size_t)gb * T * D + (size_t)(t + 1) * D + jcol);
      xa = xn.x; xb = xn.y;
    }

    // ---- poll the A-fragment data itself; on success it's already in regs ----
    const unsigned short* a0p = s + (size_t)col * D + kbase + kg;
    const unsigned short* a1p = a0p + 16 * D;
    unsigned long long ua[16], ub[16];
    for (;;) {
#pragma unroll
      for (int kk = 0; kk < 8; ++kk) {
        ua[2 * kk]     = ld_u64_llc(a0p + kk * 32);
        ua[2 * kk + 1] = ld_u64_llc(a0p + kk * 32 + 4);
        ub[2 * kk]     = ld_u64_llc(a1p + kk * 32);
        ub[2 * kk + 1] = ld_u64_llc(a1p + kk * 32 + 4);
      }
      int ok = 1;
#pragma unroll
      for (int i = 0; i < 16; ++i) {
        ok &= ((unsigned)(ua[i] >> 32) != 0xFFFFFFFFu) & ((unsigned)ua[i] != 0xFFFFFFFFu);
        ok &= ((unsigned)(ub[i] >> 32) != 0xFFFFFFFFu) & ((unsigned)ub[i] != 0xFFFFFFFFu);
      }
      if (__all(ok)) break;
    }
    __builtin_amdgcn_sched_barrier(0);

    // ---- z partial: M=32 x N=64 (4 gates x 16) x K=256 (this wave) ----
    f32x4 acc[2][4];
#pragma unroll
    for (int mt = 0; mt < 2; ++mt)
#pragma unroll
      for (int g = 0; g < 4; ++g) acc[mt][g] = (f32x4){0.f, 0.f, 0.f, 0.f};

#pragma unroll
    for (int kk = 0; kk < 8; ++kk) {
      ull2s u0, u1;
      u0.lo = ua[2 * kk]; u0.hi = ua[2 * kk + 1];
      u1.lo = ub[2 * kk]; u1.hi = ub[2 * kk + 1];
      short8 a0 = __builtin_bit_cast(short8, u0);
      short8 a1 = __builtin_bit_cast(short8, u1);
#pragma unroll
      for (int g = 0; g < 4; ++g) {
        acc[0][g] = __builtin_amdgcn_mfma_f32_16x16x32_bf16(a0, bfrag[g][kk], acc[0][g], 0, 0, 0);
        acc[1][g] = __builtin_amdgcn_mfma_f32_16x16x32_bf16(a1, bfrag[g][kk], acc[1][g], 0, 0, 0);
      }
    }

    // ---- exchange partials (C/D layout: n=lane&15, m=(lane>>4)*4+r) ----
    {
      const int zr = (lane >> 4) * 4;
#pragma unroll
      for (int g = 0; g < 4; ++g)
#pragma unroll
        for (int r = 0; r < 4; ++r) {
          zx[wave][zr + r][g * 16 + col]      = acc[0][g][r];
          zx[wave][zr + r + 16][g * 16 + col] = acc[1][g][r];
        }
    }
    __syncthreads();

    // ---- reduce 4 K-partials + gate math for (gb, jp/jp+1) ----
    float zf0, zf1, zi0, zi1, zg0, zg1, zo0, zo1;
    {
      float2 f_ = *(const float2*)&zx[0][gb][jp];
      float2 i_ = *(const float2*)&zx[0][gb][16 + jp];
      float2 g_ = *(const float2*)&zx[0][gb][32 + jp];
      float2 o_ = *(const float2*)&zx[0][gb][48 + jp];
      zf0 = f_.x; zf1 = f_.y; zi0 = i_.x; zi1 = i_.y;
      zg0 = g_.x; zg1 = g_.y; zo0 = o_.x; zo1 = o_.y;
#pragma unroll
      for (int w = 1; w < 4; ++w) {
        f_ = *(const float2*)&zx[w][gb][jp];
        i_ = *(const float2*)&zx[w][gb][16 + jp];
        g_ = *(const float2*)&zx[w][gb][32 + jp];
        o_ = *(const float2*)&zx[w][gb][48 + jp];
        zf0 += f_.x; zf1 += f_.y; zi0 += i_.x; zi1 += i_.y;
        zg0 += g_.x; zg1 += g_.y; zo0 += o_.x; zo1 += o_.y;
      }
    }

    float f0 = sigm(zf0 + bf0), f1 = sigm(zf1 + bf1);
    float i0 = sigm(zi0 + bi0) * tanh_fast(zg0 + bg0);
    float i1 = sigm(zi1 + bi1) * tanh_fast(zg1 + bg1);
    c0 = c0 * f0 + i0;
    c1 = c1 * f1 + i1;
    float h0 = sigm(zo0 + bo0) * tanh_fast(c0);
    float h1 = sigm(zo1 + bo1) * tanh_fast(c1);

    if (t + 1 < T) {
      // order reset (and all earlier vmem) before publish, then publish s_{t+1}
      asm volatile("s_waitcnt vmcnt(0)" ::: "memory");
      unsigned short* snext = sbuf + (size_t)((t + 1) & 3) * B * D;
      st_u32_llc((unsigned*)(snext + (size_t)gb * D + jcol),
                 (unsigned)f2bf(h0 + xa) | ((unsigned)f2bf(h1 + xb) << 16));
      __syncthreads();   // zx reuse guard (placed after publish, off critical path)
      *(float2*)(out + (size_t)gb * T * D + (size_t)t * D + jcol) = make_float2(h0, h1);
    } else {
      *(float2*)(out + (size_t)gb * T * D + (size_t)t * D + jcol) = make_float2(h0, h1);
      float* cT = out + (size_t)B * T * D;
      float* hT = cT + (size_t)B * D;
      *(float2*)(cT + (size_t)gb * D + jcol) = make_float2(c0, c1);
      *(float2*)(hT + (size_t)gb * D + jcol) = make_float2(h0, h1);
    }
  }
}

extern "C" void kernel_launch(void* const* d_in, const int* in_sizes, int n_in,
                              void* d_out, int out_size, void* d_ws, size_t ws_size,
                              hipStream_t stream) {
  const float* x    = (const float*)d_in[0];
  const float* W1   = (const float*)d_in[1];
  const float* b1   = (const float*)d_in[2];
  const float* W2   = (const float*)d_in[3];
  const float* b2   = (const float*)d_in[4];
  const float* W3   = (const float*)d_in[5];
  const float* b3   = (const float*)d_in[6];
  const float* W4   = (const float*)d_in[7];
  const float* b4   = (const float*)d_in[8];
  const float* bias = (const float*)d_in[9];

  unsigned short* sbuf = (unsigned short*)d_ws;   // RING*B*D bf16 = 256 KB

  // 0xFF bytes -> every u32 reads 0xFFFFFFFF (bf16 NaN pair) = "not ready"
  hipMemsetAsync(d_ws, 0xFF, (size_t)RING * B * D * sizeof(unsigned short), stream);
  hipLaunchKernelGGL(lstm_persistent, dim3(NBLK), dim3(NTHR), 0, stream,
                     x, W1, b1, W2, b2, W3, b3, W4, b4, bias,
                     (float*)d_out, sbuf);
}